// Round 2
// baseline (417.961 us; speedup 1.0000x reference)
//
#include <hip/hip_runtime.h>

// TanhTransformBack: out[r][c] = mask[c] ? atanh(min(x/3, 1-1e-7)) * 2 : x
// 2*atanh(t) == ln((1+t)/(1-t))  -> one rcp + one log, no 0.5*/2* pair.
// Pure streaming elementwise op: 256 MB in + 256 MB out, HBM-bound.
//
// R1 fix: mask arrives as int32 (harness uploads bool as integer -> const int*),
// not 1-byte bools. Round-0 byte-read garbled the per-column select
// (absmax 0.3086 == 1 - ln 2, the untransformed-column signature).

__global__ __launch_bounds__(256) void TanhTransformBack_kernel(
    const float4* __restrict__ x4,
    const int* __restrict__ mask,  // 64 x int32 (0/1)
    float4* __restrict__ out4,
    int n4) {
  // Pack the 64 int32 mask words into one 64-bit register bitmask.
  // 64 x 4B = 256 B, L1-resident after first wave; once per thread.
  unsigned long long mbits = 0ull;
#pragma unroll
  for (int c = 0; c < 64; ++c) {
    mbits |= (unsigned long long)(mask[c] != 0) << c;
  }

  const float INV_FACTOR = 1.0f / 3.0f;       // x / FACTOR, FACTOR = 3.0
  const float CLAMP_MAX = 1.0f - 1e-7f;

  const int stride = gridDim.x * blockDim.x;
  for (int e = blockIdx.x * blockDim.x + threadIdx.x; e < n4; e += stride) {
    // Row-major [N, 64]: 16 float4 per row; this float4 covers cols c0..c0+3.
    const int c0 = (e & 15) << 2;
    const float4 v = x4[e];
    float in[4] = {v.x, v.y, v.z, v.w};
    float out[4];
#pragma unroll
    for (int j = 0; j < 4; ++j) {
      const float t = fminf(in[j] * INV_FACTOR, CLAMP_MAX);
      // 2*atanh(t) = ln((1+t)/(1-t)); t in [0, 0.334) so arg in [1, 2.01).
      const float tr = __logf(__fdividef(1.0f + t, 1.0f - t));
      const bool m = (mbits >> (c0 + j)) & 1ull;   // per-column select
      out[j] = m ? tr : in[j];                      // v_cndmask, no branch
    }
    out4[e] = make_float4(out[0], out[1], out[2], out[3]);
  }
}

extern "C" void kernel_launch(void* const* d_in, const int* in_sizes, int n_in,
                              void* d_out, int out_size, void* d_ws, size_t ws_size,
                              hipStream_t stream) {
  const float* x = (const float*)d_in[0];
  const int* mask = (const int*)d_in[1];
  float* out = (float*)d_out;

  const int n = in_sizes[0];          // 64,000,000 floats
  const int n4 = n >> 2;              // 16,777,216 float4

  // 4096 blocks x 256 threads: plenty of waves for BW, 16 iters/thread.
  const int block = 256;
  const int grid = 4096;
  TanhTransformBack_kernel<<<grid, block, 0, stream>>>(
      (const float4*)x, mask, (float4*)out, n4);
}

// Round 5
// 413.505 us; speedup vs baseline: 1.0108x; 1.0108x over previous
//
#include <hip/hip_runtime.h>

// TanhTransformBack: out[r][c] = mask[c] ? atanh(min(x/3, 1-1e-7)) * 2 : x
// 2*atanh(t) == ln((1+t)/(1-t))  -> one rcp + one log.
// Pure streaming elementwise: 256 MB in + 256 MB out, HBM-bound.
// Roofline: 512 MB / 6.3 TB/s ~= 85 us.
//
// R2: bench dur_us=418 but kernel absent from profile top-5 (< 156 us) ->
// suspect dur_us includes harness re-poison fills (~2x158 us).
// R4 fix: __builtin_nontemporal_* rejects HIP's float4 (a class type);
// use a native ext_vector_type(4) float instead. Same experiment as R2/R3:
// nt loads/stores + 2x unrolled grid-stride ILP.

typedef float f32x4 __attribute__((ext_vector_type(4)));

__global__ __launch_bounds__(256) void TanhTransformBack_kernel(
    const f32x4* __restrict__ x4,
    const int* __restrict__ mask,  // 64 x int32 (0/1)
    f32x4* __restrict__ out4,
    int n4) {
  // Pack the 64 int32 mask words into one 64-bit register bitmask.
  // Uniform address, constant offsets -> scalar loads; once per thread.
  unsigned long long mbits = 0ull;
#pragma unroll
  for (int c = 0; c < 64; ++c) {
    mbits |= (unsigned long long)(mask[c] != 0) << c;
  }

  const float INV_FACTOR = 1.0f / 3.0f;  // x / FACTOR, FACTOR = 3.0
  const float CLAMP_MAX = 1.0f - 1e-7f;

  const int T = gridDim.x * blockDim.x;
  int e = blockIdx.x * blockDim.x + threadIdx.x;

  // Main loop: 2 independent float4 streams in flight (ILP).
  for (; e + T < n4; e += 2 * T) {
    const f32x4 va = __builtin_nontemporal_load(&x4[e]);
    const f32x4 vb = __builtin_nontemporal_load(&x4[e + T]);
    const int ca = (e & 15) << 2;            // cols ca..ca+3 of 64
    const int cb = ((e + T) & 15) << 2;

    f32x4 oa, ob;
#pragma unroll
    for (int j = 0; j < 4; ++j) {
      const float ta = fminf(va[j] * INV_FACTOR, CLAMP_MAX);
      const float tb = fminf(vb[j] * INV_FACTOR, CLAMP_MAX);
      const float ra = __logf(__fdividef(1.0f + ta, 1.0f - ta));
      const float rb = __logf(__fdividef(1.0f + tb, 1.0f - tb));
      oa[j] = ((mbits >> (ca + j)) & 1ull) ? ra : va[j];
      ob[j] = ((mbits >> (cb + j)) & 1ull) ? rb : vb[j];
    }
    __builtin_nontemporal_store(oa, &out4[e]);
    __builtin_nontemporal_store(ob, &out4[e + T]);
  }
  // Tail (no-op when n4 % (2*T) == 0; kept for generality).
  for (; e < n4; e += T) {
    const f32x4 v = __builtin_nontemporal_load(&x4[e]);
    const int c0 = (e & 15) << 2;
    f32x4 o;
#pragma unroll
    for (int j = 0; j < 4; ++j) {
      const float t = fminf(v[j] * INV_FACTOR, CLAMP_MAX);
      const float tr = __logf(__fdividef(1.0f + t, 1.0f - t));
      o[j] = ((mbits >> (c0 + j)) & 1ull) ? tr : v[j];
    }
    __builtin_nontemporal_store(o, &out4[e]);
  }
}

extern "C" void kernel_launch(void* const* d_in, const int* in_sizes, int n_in,
                              void* d_out, int out_size, void* d_ws, size_t ws_size,
                              hipStream_t stream) {
  const float* x = (const float*)d_in[0];
  const int* mask = (const int*)d_in[1];
  float* out = (float*)d_out;

  const int n = in_sizes[0];  // 64,000,000 floats
  const int n4 = n >> 2;      // 16,777,216 float4

  const int block = 256;
  const int grid = 4096;  // 1M threads; 16 float4/thread (8 unrolled iters)
  TanhTransformBack_kernel<<<grid, block, 0, stream>>>(
      (const f32x4*)x, mask, (f32x4*)out, n4);
}